// Round 12
// baseline (473.189 us; speedup 1.0000x reference)
//
#include <hip/hip_runtime.h>
#include <hip/hip_bf16.h>
#include <stdint.h>

typedef __bf16 bf16_t;
typedef __bf16 bf16x8 __attribute__((ext_vector_type(8)));
typedef float f32x4 __attribute__((ext_vector_type(4)));

#define HIDN 1024
#define NHEAD 8
#define HDIM 128
#define NBATCH 8
#define LQLEN 4096
#define LKLEN 128

__device__ __forceinline__ void gload_lds16(const void* g, void* l) {
  __builtin_amdgcn_global_load_lds(
      (const __attribute__((address_space(1))) unsigned int*)g,
      (__attribute__((address_space(3))) unsigned int*)l, 16, 0, 0);
}

// ---------------------------------------------------------------------------
// Batched f32 -> bf16 convert: 7 segments, each exactly 1M elements
// ---------------------------------------------------------------------------
__global__ __launch_bounds__(256) void convk7(
    const float* s0, const float* s1, const float* s2, const float* s3,
    const float* s4, const float* s5, const float* s6,
    bf16_t* d0, bf16_t* d1, bf16_t* d2, bf16_t* d3,
    bf16_t* d4, bf16_t* d5, bf16_t* d6) {
  const float* src; bf16_t* dst;
  switch (blockIdx.y) {
    case 0: src = s0; dst = d0; break;
    case 1: src = s1; dst = d1; break;
    case 2: src = s2; dst = d2; break;
    case 3: src = s3; dst = d3; break;
    case 4: src = s4; dst = d4; break;
    case 5: src = s5; dst = d5; break;
    default: src = s6; dst = d6; break;
  }
  const int n4 = (1024 * 1024) / 4;
  const int stride = gridDim.x * 256;
  for (int i = blockIdx.x * 256 + threadIdx.x; i < n4; i += stride) {
    const float4 v = ((const float4*)src)[i];
    bf16x8 o;
    o[0] = (bf16_t)v.x; o[1] = (bf16_t)v.y; o[2] = (bf16_t)v.z; o[3] = (bf16_t)v.w;
    *(uint2*)((char*)dst + (size_t)i * 8) = *(uint2*)&o;
  }
}

// ---------------------------------------------------------------------------
// m97-frame GEMM (R12): C[32768,1024] = A @ Bw^T + bias.
// 128x128 tile, 256 threads = 4 waves (2x2), wave-tile 64x64 (acc 64 VGPR),
// BK=32, SINGLE-buffered LDS, exact m97 2-barrier loop.  LDS 32KB total ->
// 3-4 blocks/CU co-resident (m114 cross-block overlap = m97's 874-912 TF
// mechanism that every 128KB/1-block phased variant lacked).
// Swizzle: R5-verified 0-conflict pattern, both-sides.
// AF32: A staged RAW f32 via global_load_lds (16KB/tile), converted bf16 on
//   fragment read (compiler packs casts to cvt_pk; no hand vmcnt ledger).
// XCD-patch grid (R3): 2048 blocks/GEMM, xcd=bid&7 owns 32m x 8n, n fastest.
// MODE 0: bf16 [B,H,4096,128] via per-wave-8KB LDS-staged coalesced store.
// MODE 2: f32 row-major direct.
// ---------------------------------------------------------------------------
template <int MODE, bool AF32>
__device__ __forceinline__ void gemm97_body(const void* __restrict__ Asrc,
                                            const bf16_t* __restrict__ Bw,
                                            const float* __restrict__ bias,
                                            void* __restrict__ Cout,
                                            char* smem, int bid) {
  constexpr int ASZ = AF32 ? 16384 : 8192;  // A tile bytes (f32 or bf16)
  const int tid = threadIdx.x;
  const int wid = tid >> 6, lane = tid & 63;
  const int lr = lane & 15, lh = lane >> 4;
  const int wr = wid >> 1, wc = wid & 1;  // wave grid 2 (M) x 2 (N)

  const int idx = bid >> 3;
  const int m_blk = (bid & 7) * 32 + (idx >> 3);
  const int n_blk = idx & 7;
  const int m0 = m_blk * 128, n0 = n_blk * 128;

  // ---- B staging: 8KB = 512 16B-chunks, 2/thread; row=c>>2, slot=c&3,
  // linear LDS dest, source slot inverse-swizzled (R5).
  const char* srcB[2];
  int dB[2];
#pragma unroll
  for (int i = 0; i < 2; ++i) {
    const int c = tid + 256 * i;
    const int sl = (c & 3) ^ ((c >> 3) & 3);
    srcB[i] = (const char*)Bw + (size_t)(n0 + (c >> 2)) * 2048 + (sl << 4);
    dB[i] = ASZ + c * 16;
  }

  // ---- A staging
  const char* srcA[4];
  int dA[4];
  if constexpr (AF32) {
    // 16KB f32 = 1024 chunks, 4/thread; row=c>>3 (128B rows, 8 slots)
#pragma unroll
    for (int i = 0; i < 4; ++i) {
      const int c = tid + 256 * i;
      const int sl = (c & 7) ^ ((c >> 3) & 7);
      srcA[i] = (const char*)Asrc + (size_t)(m0 + (c >> 3)) * 4096 + (sl << 4);
      dA[i] = c * 16;
    }
  } else {
#pragma unroll
    for (int i = 0; i < 2; ++i) {
      const int c = tid + 256 * i;
      const int sl = (c & 3) ^ ((c >> 3) & 3);
      srcA[i] = (const char*)Asrc + (size_t)(m0 + (c >> 2)) * 2048 + (sl << 4);
      dA[i] = c * 16;
    }
  }

  f32x4 acc[4][4] = {};

  // ---- read-side offsets
  const int swz = ((lr >> 1) & 3) << 4;  // bf16 64B rows (4 slots)
  const int boff = ASZ + (wc * 64 + lr) * 64 + ((lh << 4) ^ swz);
  const int aoff_bf = (wr * 64 + lr) * 64 + ((lh << 4) ^ swz);
  const int arow_f32 = (wr * 64 + lr) * 128;       // f32 128B rows (8 slots)
  const int asl0 = (((2 * lh) ^ (lr & 7)) << 4);   // k = 8*lh .. +4
  const int asl1 = (((2 * lh + 1) ^ (lr & 7)) << 4);  // k = 8*lh+4 .. +8

  for (int k0 = 0; k0 < HIDN; k0 += 32) {
    if constexpr (AF32) {
#pragma unroll
      for (int i = 0; i < 4; ++i) gload_lds16(srcA[i] + k0 * 4, smem + dA[i]);
    } else {
#pragma unroll
      for (int i = 0; i < 2; ++i) gload_lds16(srcA[i] + k0 * 2, smem + dA[i]);
    }
    gload_lds16(srcB[0] + k0 * 2, smem + dB[0]);
    gload_lds16(srcB[1] + k0 * 2, smem + dB[1]);
    __syncthreads();  // compiler emits vmcnt(0) drain before the barrier

    bf16x8 af[4], bfr[4];
#pragma unroll
    for (int i = 0; i < 4; ++i) {
      if constexpr (AF32) {
        const char* p = smem + arow_f32 + i * 2048;
        const f32x4 lo = *(const f32x4*)(p + asl0);
        const f32x4 hi = *(const f32x4*)(p + asl1);
        bf16x8 w;
        w[0] = (bf16_t)lo[0]; w[1] = (bf16_t)lo[1];
        w[2] = (bf16_t)lo[2]; w[3] = (bf16_t)lo[3];
        w[4] = (bf16_t)hi[0]; w[5] = (bf16_t)hi[1];
        w[6] = (bf16_t)hi[2]; w[7] = (bf16_t)hi[3];
        af[i] = w;
      } else {
        af[i] = *(const bf16x8*)(smem + aoff_bf + i * 1024);
      }
      bfr[i] = *(const bf16x8*)(smem + boff + i * 1024);
    }
#pragma unroll
    for (int i = 0; i < 4; ++i)
#pragma unroll
      for (int j = 0; j < 4; ++j)
        acc[i][j] = __builtin_amdgcn_mfma_f32_16x16x32_bf16(af[i], bfr[j], acc[i][j], 0, 0, 0);
    __syncthreads();  // protect LDS before next-iter staging
  }

  // ---- epilogue. C/D layout: col = lane&15, row = (lane>>4)*4 + reg.
  if constexpr (MODE == 2) {
    float* C = (float*)Cout;
#pragma unroll
    for (int f = 0; f < 4; ++f) {
      const int gm = m0 + wr * 64 + f * 16 + lh * 4;
#pragma unroll
      for (int j = 0; j < 4; ++j) {
        const int gn = n0 + wc * 64 + j * 16 + lr;
        const float bb = bias[gn];
#pragma unroll
        for (int r = 0; r < 4; ++r)
          C[(size_t)(gm + r) * HIDN + gn] = acc[f][j][r] + bb;
      }
    }
  } else {
    // per-wave 8KB LDS-staged coalesced bf16 store (4 x 8KB = 32KB)
    char* wlds = smem + wid * 8192;  // 64 rows x 128B
#pragma unroll
    for (int f = 0; f < 4; ++f) {
#pragma unroll
      for (int j = 0; j < 4; ++j) {
        const int gn = n0 + wc * 64 + j * 16 + lr;
        const float bb = bias[gn];
#pragma unroll
        for (int r = 0; r < 4; ++r)
          *(bf16_t*)(wlds + (f * 16 + lh * 4 + r) * 128 + (j * 16 + lr) * 2) =
              (bf16_t)(acc[f][j][r] + bb);
      }
    }
    asm volatile("s_waitcnt lgkmcnt(0)" ::: "memory");
    __builtin_amdgcn_sched_barrier(0);
    bf16_t* C = (bf16_t*)Cout;
    const int gnb = n0 + wc * 64;
    const int h = gnb >> 7, dd = gnb & 127;
#pragma unroll
    for (int p = 0; p < 8; ++p) {
      const int rl = p * 8 + (lane >> 3);  // local row 0..63
      const int cb = (lane & 7) * 16;      // byte col 0..112
      const uint4 v = *(const uint4*)(wlds + rl * 128 + cb);
      const int gm = m0 + wr * 64 + rl;
      const int b = gm >> 12, l = gm & 4095;
      *(uint4*)((char*)(C + (((size_t)(b * NHEAD + h) * LQLEN + l) << 7) + dd) + cb) = v;
    }
  }
}

// Merged Q-proj + A-proj: blocks [0,2048) -> query, [2048,4096) -> atten.
__global__ __launch_bounds__(256) void gemm_qa(
    const float* __restrict__ Aq, const bf16_t* __restrict__ Wq,
    const float* __restrict__ bq, bf16_t* __restrict__ Qh,
    const float* __restrict__ Aa, const bf16_t* __restrict__ Wa,
    const float* __restrict__ ba, bf16_t* __restrict__ Ah) {
  __shared__ uint4 smem_raw[2048];  // 32KB
  const int bid = blockIdx.x;
  if (bid < 2048)
    gemm97_body<0, true>(Aq, Wq, bq, (void*)Qh, (char*)smem_raw, bid);
  else
    gemm97_body<0, true>(Aa, Wa, ba, (void*)Ah, (char*)smem_raw, bid - 2048);
}

// FC GEMM (bf16 A path)
__global__ __launch_bounds__(256) void gemm_fc(const bf16_t* __restrict__ A,
                                               const bf16_t* __restrict__ Bw,
                                               const float* __restrict__ bias,
                                               float* __restrict__ Cout) {
  __shared__ uint4 smem_raw[2048];  // 32KB
  gemm97_body<2, false>(A, Bw, bias, (void*)Cout, (char*)smem_raw, blockIdx.x);
}

// ---------------------------------------------------------------------------
// Merged K+V projections (M = 1024): z=0 -> K (head layout), z=1 -> V (V^T)
// ---------------------------------------------------------------------------
__global__ __launch_bounds__(256) void gemm_btkv(
    const bf16_t* __restrict__ kA, const bf16_t* __restrict__ kW,
    const float* __restrict__ kb_, bf16_t* __restrict__ Kh,
    const bf16_t* __restrict__ vA, const bf16_t* __restrict__ vW,
    const float* __restrict__ vb_, bf16_t* __restrict__ Vt) {
  constexpr int BK = 32;
  __shared__ uint4 AsRaw[128 * BK * 2 / 16];
  __shared__ uint4 BsRaw[128 * BK * 2 / 16];
  bf16_t* As = (bf16_t*)AsRaw;
  bf16_t* Bs = (bf16_t*)BsRaw;

  const bool isV = (blockIdx.z == 1);
  const bf16_t* A = isV ? vA : kA;
  const bf16_t* Bw = isV ? vW : kW;
  const float* bias = isV ? vb_ : kb_;
  bf16_t* Cout = isV ? Vt : Kh;

  const int tid = threadIdx.x;
  const int wid = tid >> 6;
  const int lane = tid & 63;
  const int lr = lane & 15, lh = lane >> 4;
  const int m0 = blockIdx.x * 128, n0 = blockIdx.y * 128;
  const int wm = (wid >> 1) * 64, wn = (wid & 1) * 64;

  f32x4 acc[4][4] = {};

  const int srow = lane >> 2;
  const int scol = (lane & 3) * 16;

  for (int k0 = 0; k0 < HIDN; k0 += BK) {
#pragma unroll
    for (int i = 0; i < 2; ++i) {
      const int c = wid + i * 4;
      const int row = c * 16 + srow;
      gload_lds16((const char*)A + ((size_t)(m0 + row) * HIDN + k0) * 2 + scol,
                  (char*)As + c * 1024);
      gload_lds16((const char*)Bw + ((size_t)(n0 + row) * HIDN + k0) * 2 + scol,
                  (char*)Bs + c * 1024);
    }
    __syncthreads();

    bf16x8 af[4], bfr[4];
#pragma unroll
    for (int i = 0; i < 4; ++i) {
      af[i]  = *(const bf16x8*)(As + (wm + i * 16 + lr) * BK + lh * 8);
      bfr[i] = *(const bf16x8*)(Bs + (wn + i * 16 + lr) * BK + lh * 8);
    }
#pragma unroll
    for (int i = 0; i < 4; ++i)
#pragma unroll
      for (int j = 0; j < 4; ++j)
        acc[i][j] = __builtin_amdgcn_mfma_f32_16x16x32_bf16(af[i], bfr[j], acc[i][j], 0, 0, 0);
    __syncthreads();
  }

#pragma unroll
  for (int i = 0; i < 4; ++i) {
#pragma unroll
    for (int r = 0; r < 4; ++r) {
      const int gm = m0 + wm + i * 16 + lh * 4 + r;
#pragma unroll
      for (int j = 0; j < 4; ++j) {
        const int gn = n0 + wn + j * 16 + lr;
        const float v = acc[i][j][r] + bias[gn];
        const int b = gm >> 7, l = gm & 127;
        const int h = gn >> 7, d = gn & 127;
        size_t idx;
        if (!isV)
          idx = (((size_t)(b * NHEAD + h) * 128 + l) << 7) + d;
        else
          idx = (((size_t)(b * NHEAD + h) * 128 + d) << 7) + l;
        Cout[idx] = (bf16_t)v;
      }
    }
  }
}

// ---------------------------------------------------------------------------
// Fused attention (R11-proven): K/V via gload_lds with pre-swizzled source,
// Ah via gload_lds into dead K-LDS, coalesced X store via dead V-LDS.
// ---------------------------------------------------------------------------
__global__ __launch_bounds__(256) void attn_kernel(
    const bf16_t* __restrict__ Qh, const bf16_t* __restrict__ Ah,
    const bf16_t* __restrict__ Kh, const bf16_t* __restrict__ Vt,
    const int* __restrict__ mask, bf16_t* __restrict__ X) {
  __shared__ uint4 KsRaw[2048];
  __shared__ uint4 VsRaw[2048];
  __shared__ float Ms[128];
  char* Ks = (char*)KsRaw;
  char* Vs = (char*)VsRaw;

  const int tid = threadIdx.x, wid = tid >> 6, lane = tid & 63;
  const int lr = lane & 15, lh = lane >> 4;
  const int bh = blockIdx.y, b = bh >> 3, h = bh & 7;
  const int q0 = blockIdx.x * 64;

  {
    const char* Kg = (const char*)(Kh + (size_t)bh * 16384);
    const char* Vg = (const char*)(Vt + (size_t)bh * 16384);
#pragma unroll
    for (int it = 0; it < 8; ++it) {
      const int e = it * 256 + tid;
      const int row = e >> 4;
      const int cbp = (e & 15) << 4;
      const int srcoff = row * 256 + (cbp ^ ((row & 7) << 4));
      gload_lds16(Kg + srcoff, Ks + e * 16);
      gload_lds16(Vg + srcoff, Vs + e * 16);
    }
  }
  if (tid < 128) Ms[tid] = (mask[b * 128 + tid] == 0) ? 0.f : 1.f;

  bf16x8 qf[4];
  {
    const bf16_t* Qb = Qh + ((size_t)bh * LQLEN + q0 + wid * 16 + lr) * 128;
#pragma unroll
    for (int s = 0; s < 4; ++s) qf[s] = *(const bf16x8*)(Qb + s * 32 + lh * 8);
  }
  asm volatile("s_waitcnt vmcnt(0)" ::: "memory");
  __syncthreads();

  f32x4 acc[8] = {};
#pragma unroll
  for (int nt = 0; nt < 8; ++nt) {
#pragma unroll
    for (int s = 0; s < 4; ++s) {
      const int row = nt * 16 + lr;
      const int cb = (s * 64 + lh * 16) ^ ((row & 7) << 4);
      const bf16x8 kf = *(const bf16x8*)(Ks + row * 256 + cb);
      acc[nt] = __builtin_amdgcn_mfma_f32_16x16x32_bf16(qf[s], kf, acc[nt], 0, 0, 0);
    }
  }
  __syncthreads();

  {
    const char* Ag = (const char*)(Ah + ((size_t)bh * LQLEN + q0) * 128);
#pragma unroll
    for (int it = 0; it < 4; ++it) {
      const int c = it * 256 + tid;
      gload_lds16(Ag + c * 16, Ks + 16384 + c * 16);
    }
  }
  asm volatile("s_waitcnt vmcnt(0)" ::: "memory");
  __syncthreads();
  const char* Al = Ks + 16384;

  float ex[8][4];
  float rsum[4];
  const float sc = 0.08838834764831845f;
#pragma unroll
  for (int r = 0; r < 4; ++r) {
    const int row = lh * 4 + r;
    const int rowg = wid * 16 + row;
    float mx = -3.0e38f;
#pragma unroll
    for (int nt = 0; nt < 8; ++nt) {
      const int col = nt * 16 + lr;
      float e = acc[nt][r] * sc + (float)(*(const bf16_t*)(Al + rowg * 256 + col * 2));
      e = (Ms[col] != 0.f) ? e : -1.0e10f;
      ex[nt][r] = e;
      mx = fmaxf(mx, e);
    }
    mx = fmaxf(mx, __shfl_xor(mx, 1));
    mx = fmaxf(mx, __shfl_xor(mx, 2));
    mx = fmaxf(mx, __shfl_xor(mx, 4));
    mx = fmaxf(mx, __shfl_xor(mx, 8));
    float s_ = 0.f;
#pragma unroll
    for (int nt = 0; nt < 8; ++nt) {
      const float p = expf(ex[nt][r] - mx);
      ex[nt][r] = p;
      s_ += p;
    }
    s_ += __shfl_xor(s_, 1);
    s_ += __shfl_xor(s_, 2);
    s_ += __shfl_xor(s_, 4);
    s_ += __shfl_xor(s_, 8);
    rsum[r] = s_;
  }

  char* Pb = Ks + wid * 4096;
#pragma unroll
  for (int r = 0; r < 4; ++r) {
    const int row = lh * 4 + r;
#pragma unroll
    for (int nt = 0; nt < 8; ++nt) {
      const int col = nt * 16 + lr;
      const int off = (row * 256 + col * 2) ^ ((row & 7) << 4);
      *(bf16_t*)(Pb + off) = (bf16_t)ex[nt][r];
    }
  }
  __syncthreads();

  bf16x8 pf[4];
#pragma unroll
  for (int s = 0; s < 4; ++s)
    pf[s] = *(const bf16x8*)(Pb + lr * 256 + ((s * 64 + lh * 16) ^ ((lr & 7) << 4)));
  f32x4 acc2[8] = {};
#pragma unroll
  for (int nt = 0; nt < 8; ++nt) {
#pragma unroll
    for (int s = 0; s < 4; ++s) {
      const int row = nt * 16 + lr;
      const int cb = (s * 64 + lh * 16) ^ ((row & 7) << 4);
      const bf16x8 vf = *(const bf16x8*)(Vs + row * 256 + cb);
      acc2[nt] = __builtin_amdgcn_mfma_f32_16x16x32_bf16(pf[s], vf, acc2[nt], 0, 0, 0);
    }
  }
  __syncthreads();

  float rs[4];
#pragma unroll
  for (int r = 0; r < 4; ++r) rs[r] = 1.f / rsum[r];
#pragma unroll
  for (int nt = 0; nt < 8; ++nt)
#pragma unroll
    for (int r = 0; r < 4; ++r)
      *(bf16_t*)(Vs + (wid * 16 + lh * 4 + r) * 256 + (nt * 16 + lr) * 2) =
          (bf16_t)(acc2[nt][r] * rs[r]);
  asm volatile("s_waitcnt lgkmcnt(0)" ::: "memory");
  __syncthreads();

#pragma unroll
  for (int it = 0; it < 4; ++it) {
    const int c = it * 256 + tid;
    const int row = c >> 4;
    const int off = (c & 15) << 4;
    const uint4 v = *(const uint4*)(Vs + row * 256 + off);
    char* dstp = (char*)(X + ((size_t)(b * LQLEN) + q0 + row) * HIDN + h * 128) + off;
    *(uint4*)dstp = v;
  }
}

// ---------------------------------------------------------------------------
extern "C" void kernel_launch(void* const* d_in, const int* in_sizes, int n_in,
                              void* d_out, int out_size, void* d_ws, size_t ws_size,
                              hipStream_t stream) {
  const float* query = (const float*)d_in[0];
  const float* key   = (const float*)d_in[1];
  const float* value = (const float*)d_in[2];
  const float* atten = (const float*)d_in[3];
  const int*   mask  = (const int*)d_in[4];
  const float* Wq  = (const float*)d_in[5];  const float* bq   = (const float*)d_in[6];
  const float* Wk  = (const float*)d_in[7];  const float* bk   = (const float*)d_in[8];
  const float* Wv  = (const float*)d_in[9];  const float* bv   = (const float*)d_in[10];
  const float* Wat = (const float*)d_in[11]; const float* batt = (const float*)d_in[12];
  const float* Wfc = (const float*)d_in[13]; const float* bfc  = (const float*)d_in[14];

  char* ws = (char*)d_ws;
  bf16_t* X   = (bf16_t*)(ws + 0x0000000);   // 64MB [B,LQ,HID] bf16 (attn out)
  bf16_t* Qh  = (bf16_t*)(ws + 0x8000000);   // 64MB [B,H,LQ,HD]
  bf16_t* Ah  = (bf16_t*)(ws + 0xC000000);   // 64MB
  char* sm = ws + 0x10000000;
  bf16_t* kbf = (bf16_t*)(sm + 0x000000);
  bf16_t* vbf = (bf16_t*)(sm + 0x200000);
  bf16_t* wqb = (bf16_t*)(sm + 0x400000);
  bf16_t* wkb = (bf16_t*)(sm + 0x600000);
  bf16_t* wvb = (bf16_t*)(sm + 0x800000);
  bf16_t* wab = (bf16_t*)(sm + 0xA00000);
  bf16_t* wfb = (bf16_t*)(sm + 0xC00000);
  bf16_t* Kh  = (bf16_t*)(sm + 0xE00000);
  bf16_t* Vt  = (bf16_t*)(sm + 0x1000000);

  // single batched convert: key, value, 5 weights (1M elems each)
  convk7<<<dim3(256, 7), dim3(256), 0, stream>>>(
      key, value, Wq, Wk, Wv, Wat, Wfc,
      kbf, vbf, wqb, wkb, wvb, wab, wfb);

  // merged K/V projections (one dispatch)
  gemm_btkv<<<dim3(8, 8, 2), dim3(256), 0, stream>>>(
      kbf, wkb, bk, Kh, vbf, wvb, bv, Vt);

  // merged Q-proj + A-proj (one dispatch, fused f32 convert, m97 frame)
  gemm_qa<<<dim3(4096), dim3(256), 0, stream>>>(
      query, wqb, bq, Qh, atten, wab, batt, Ah);

  // fused attention
  attn_kernel<<<dim3(LQLEN / 64, NBATCH * NHEAD), dim3(256), 0, stream>>>(
      Qh, Ah, Kh, Vt, mask, X);

  // final FC -> f32 out (m97 frame)
  gemm_fc<<<dim3(2048), dim3(256), 0, stream>>>(X, wfb, bfc, (float*)d_out);
}

// Round 13
// 375.531 us; speedup vs baseline: 1.2601x; 1.2601x over previous
//
#include <hip/hip_runtime.h>
#include <hip/hip_bf16.h>
#include <stdint.h>

typedef __bf16 bf16_t;
typedef __bf16 bf16x8 __attribute__((ext_vector_type(8)));
typedef float f32x4 __attribute__((ext_vector_type(4)));

#define HIDN 1024
#define NHEAD 8
#define HDIM 128
#define NBATCH 8
#define LQLEN 4096
#define LKLEN 128

__device__ __forceinline__ void gload_lds16(const void* g, void* l) {
  __builtin_amdgcn_global_load_lds(
      (const __attribute__((address_space(1))) unsigned int*)g,
      (__attribute__((address_space(3))) unsigned int*)l, 16, 0, 0);
}

// ---------------------------------------------------------------------------
// Batched f32 -> bf16 convert: 7 segments, each exactly 1M elements
// ---------------------------------------------------------------------------
__global__ __launch_bounds__(256) void convk7(
    const float* s0, const float* s1, const float* s2, const float* s3,
    const float* s4, const float* s5, const float* s6,
    bf16_t* d0, bf16_t* d1, bf16_t* d2, bf16_t* d3,
    bf16_t* d4, bf16_t* d5, bf16_t* d6) {
  const float* src; bf16_t* dst;
  switch (blockIdx.y) {
    case 0: src = s0; dst = d0; break;
    case 1: src = s1; dst = d1; break;
    case 2: src = s2; dst = d2; break;
    case 3: src = s3; dst = d3; break;
    case 4: src = s4; dst = d4; break;
    case 5: src = s5; dst = d5; break;
    default: src = s6; dst = d6; break;
  }
  const int n4 = (1024 * 1024) / 4;
  const int stride = gridDim.x * 256;
  for (int i = blockIdx.x * 256 + threadIdx.x; i < n4; i += stride) {
    const float4 v = ((const float4*)src)[i];
    bf16x8 o;
    o[0] = (bf16_t)v.x; o[1] = (bf16_t)v.y; o[2] = (bf16_t)v.z; o[3] = (bf16_t)v.w;
    *(uint2*)((char*)dst + (size_t)i * 8) = *(uint2*)&o;
  }
}

// ---------------------------------------------------------------------------
// Phased big GEMM body (R11-proven): C[32768,1024] = A @ Bw^T + bias.
// BM=BN=256, BK=32, 8 waves (2M x 4N), wave-tile 128x64, ring-of-4 LDS,
// R5-verified 0-conflict K-loop swizzle, counted vmcnt ledger (R11).
// R13: MODE-0 epilogue wlds now XOR-swizzled both sides (kills the 8-way
// scalar-write conflict that was the 2^21 SQ_LDS_BANK_CONFLICT signature).
// ---------------------------------------------------------------------------
template <int MODE, bool AF32>
__device__ __forceinline__ void gemm8p_body(const void* __restrict__ Asrc,
                                            const bf16_t* __restrict__ Bw,
                                            const float* __restrict__ bias,
                                            void* __restrict__ Cout,
                                            char* smem, int bid) {
  constexpr int NT = 32;
  constexpr int SLOT = 32768;

  const int tid = threadIdx.x;
  const int wid = tid >> 6, lane = tid & 63;
  const int lr = lane & 15, lh = lane >> 4;
  const int wr = wid >> 2, wc = wid & 3;

  const int m_blk = (bid & 7) * 16 + (bid >> 5);
  const int n_blk = (bid >> 3) & 3;
  const int m0 = m_blk * 256, n0 = n_blk * 256;

  const int c0 = tid, c1 = tid + 512;
  const int sl0 = ((c0 & 3) ^ ((c0 >> 3) & 3));
  const int sl1 = ((c1 & 3) ^ ((c1 >> 3) & 3));
  const char* srcB0 = (const char*)Bw + (size_t)(n0 + (c0 >> 2)) * 2048 + (sl0 << 4);
  const char* srcB1 = (const char*)Bw + (size_t)(n0 + (c1 >> 2)) * 2048 + (sl1 << 4);
  const int dA0 = c0 * 16, dA1 = c1 * 16;
  const int dB0 = 16384 + c0 * 16, dB1 = 16384 + c1 * 16;

  f32x4 acc[8][4] = {};

  const int swz = ((lr >> 1) & 3) << 4;
  const int aoff = (wr * 128 + lr) * 64 + ((lh << 4) ^ swz);
  const int boff = 16384 + (wc * 64 + lr) * 64 + ((lh << 4) ^ swz);

#define GLOADB(T)                                                     \
  do {                                                                \
    char* bdst = smem + (((T) & 3) * SLOT) + 16384;                   \
    gload_lds16(srcB0 + (T) * 64, bdst + dA0);                        \
    gload_lds16(srcB1 + (T) * 64, bdst + dA1);                        \
  } while (0)

  if constexpr (AF32) {
    const char* srcAf0 = (const char*)Asrc + (size_t)(m0 + (c0 >> 2)) * 4096 + sl0 * 32;
    const char* srcAf1 = (const char*)Asrc + (size_t)(m0 + (c1 >> 2)) * 4096 + sl1 * 32;

    f32x4 eA0, eA1, eA2, eA3, oA0, oA1, oA2, oA3;

#define ISSUE_A(R0, R1, R2, R3, T)                                    \
  do {                                                                \
    R0 = *(const f32x4*)(srcAf0 + (T) * 128);                         \
    R1 = *(const f32x4*)(srcAf0 + (T) * 128 + 16);                    \
    R2 = *(const f32x4*)(srcAf1 + (T) * 128);                         \
    R3 = *(const f32x4*)(srcAf1 + (T) * 128 + 16);                    \
  } while (0)

#define WRITE_A(SL, R0, R1, R2, R3)                                   \
  do {                                                                \
    bf16x8 w0, w1;                                                    \
    w0[0] = (bf16_t)R0[0]; w0[1] = (bf16_t)R0[1];                     \
    w0[2] = (bf16_t)R0[2]; w0[3] = (bf16_t)R0[3];                     \
    w0[4] = (bf16_t)R1[0]; w0[5] = (bf16_t)R1[1];                     \
    w0[6] = (bf16_t)R1[2]; w0[7] = (bf16_t)R1[3];                     \
    w1[0] = (bf16_t)R2[0]; w1[1] = (bf16_t)R2[1];                     \
    w1[2] = (bf16_t)R2[2]; w1[3] = (bf16_t)R2[3];                     \
    w1[4] = (bf16_t)R3[0]; w1[5] = (bf16_t)R3[1];                     \
    w1[6] = (bf16_t)R3[2]; w1[7] = (bf16_t)R3[3];                     \
    *(bf16x8*)(smem + (SL) * SLOT + dA0) = w0;                        \
    *(bf16x8*)(smem + (SL) * SLOT + dA1) = w1;                        \
  } while (0)

    // ---- prologue (B-first ordering)
    GLOADB(0); GLOADB(1); GLOADB(2);
    ISSUE_A(eA0, eA1, eA2, eA3, 0);
    ISSUE_A(oA0, oA1, oA2, oA3, 1);
    asm volatile("" ::: "memory");
    asm volatile("s_waitcnt vmcnt(0)" ::: "memory");
    WRITE_A(0, eA0, eA1, eA2, eA3);
    WRITE_A(1, oA0, oA1, oA2, oA3);
    ISSUE_A(eA0, eA1, eA2, eA3, 2);
    ISSUE_A(oA0, oA1, oA2, oA3, 3);
    asm volatile("" ::: "memory");
    asm volatile("s_waitcnt vmcnt(8) lgkmcnt(0)" ::: "memory");
    __builtin_amdgcn_s_barrier();
    __builtin_amdgcn_sched_barrier(0);

#define GTILE(T, R0, R1, R2, R3)                                          \
  do {                                                                    \
    const char* sA = smem + ((T) & 3) * SLOT + aoff;                      \
    const char* sB = smem + ((T) & 3) * SLOT + boff;                      \
    if ((T) <= NT - 3) WRITE_A(((T) + 2) & 3, R0, R1, R2, R3);            \
    if ((T) <= NT - 4) GLOADB((T) + 3);                                   \
    if ((T) <= NT - 5) ISSUE_A(R0, R1, R2, R3, (T) + 4);                  \
    bf16x8 bfr[4], af[8];                                                 \
    _Pragma("unroll") for (int n = 0; n < 4; ++n)                         \
        bfr[n] = *(const bf16x8*)(sB + n * 1024);                         \
    _Pragma("unroll") for (int m = 0; m < 8; ++m)                         \
        af[m] = *(const bf16x8*)(sA + m * 1024);                          \
    __builtin_amdgcn_s_setprio(1);                                        \
    _Pragma("unroll") for (int m = 0; m < 8; ++m)                         \
        _Pragma("unroll") for (int n = 0; n < 4; ++n)                     \
            acc[m][n] = __builtin_amdgcn_mfma_f32_16x16x32_bf16(          \
                af[m], bfr[n], acc[m][n], 0, 0, 0);                       \
    __builtin_amdgcn_s_setprio(0);                                        \
    if ((T) < NT - 1) {                                                   \
      __builtin_amdgcn_sched_barrier(0);                                  \
      if ((T) <= NT - 5)                                                  \
        asm volatile("s_waitcnt vmcnt(10) lgkmcnt(0)" ::: "memory");      \
      else if ((T) == NT - 4)                                             \
        asm volatile("s_waitcnt vmcnt(2) lgkmcnt(0)" ::: "memory");       \
      else                                                                \
        asm volatile("s_waitcnt vmcnt(0) lgkmcnt(0)" ::: "memory");       \
      __builtin_amdgcn_s_barrier();                                       \
      __builtin_amdgcn_sched_barrier(0);                                  \
    }                                                                     \
  } while (0)

    for (int tt = 0; tt < NT / 2; ++tt) {
      GTILE(2 * tt, eA0, eA1, eA2, eA3);
      GTILE(2 * tt + 1, oA0, oA1, oA2, oA3);
    }
#undef GTILE
#undef ISSUE_A
#undef WRITE_A
  } else {
    const char* srcA0 = (const char*)Asrc + (size_t)(m0 + (c0 >> 2)) * 2048 + (sl0 << 4);
    const char* srcA1 = (const char*)Asrc + (size_t)(m0 + (c1 >> 2)) * 2048 + (sl1 << 4);
#pragma unroll
    for (int tt = 0; tt < 3; ++tt) {
      char* dst = smem + tt * SLOT;
      gload_lds16(srcA0 + tt * 64, dst + dA0);
      gload_lds16(srcA1 + tt * 64, dst + dA1);
      gload_lds16(srcB0 + tt * 64, dst + dB0);
      gload_lds16(srcB1 + tt * 64, dst + dB1);
    }
    asm volatile("s_waitcnt vmcnt(8)" ::: "memory");
    __builtin_amdgcn_s_barrier();
    __builtin_amdgcn_sched_barrier(0);

    for (int t = 0; t < NT; ++t) {
      const char* sA = smem + (t & 3) * SLOT + aoff;
      const char* sB = smem + (t & 3) * SLOT + boff;
      char* dst = smem + ((t + 3) & 3) * SLOT;
      const int kb = (t + 3) * 64;
      const bool pf = (t <= NT - 4);

      bf16x8 bfr[4], af[8];
#pragma unroll
      for (int n = 0; n < 4; ++n) bfr[n] = *(const bf16x8*)(sB + n * 1024);
#pragma unroll
      for (int m = 0; m < 8; ++m) af[m] = *(const bf16x8*)(sA + m * 1024);
      if (pf) {
        gload_lds16(srcA0 + kb, dst + dA0);
        gload_lds16(srcA1 + kb, dst + dA1);
        gload_lds16(srcB0 + kb, dst + dB0);
        gload_lds16(srcB1 + kb, dst + dB1);
      }
      __builtin_amdgcn_s_setprio(1);
#pragma unroll
      for (int m = 0; m < 8; ++m)
#pragma unroll
        for (int n = 0; n < 4; ++n)
          acc[m][n] = __builtin_amdgcn_mfma_f32_16x16x32_bf16(af[m], bfr[n], acc[m][n], 0, 0, 0);
      __builtin_amdgcn_s_setprio(0);

      if (t < NT - 1) {
        __builtin_amdgcn_sched_barrier(0);
        if (t <= NT - 4)
          asm volatile("s_waitcnt vmcnt(8)" ::: "memory");
        else if (t == NT - 3)
          asm volatile("s_waitcnt vmcnt(4)" ::: "memory");
        else
          asm volatile("s_waitcnt vmcnt(0)" ::: "memory");
        __builtin_amdgcn_s_barrier();
        __builtin_amdgcn_sched_barrier(0);
      }
    }
  }
#undef GLOADB

  // ---- epilogue. C/D layout: col = lane&15, row = (lane>>4)*4 + reg.
  if constexpr (MODE == 2) {
    float* C = (float*)Cout;
#pragma unroll
    for (int f = 0; f < 8; ++f) {
      const int gm = m0 + wr * 128 + f * 16 + lh * 4;
#pragma unroll
      for (int j = 0; j < 4; ++j) {
        const int gn = n0 + wc * 64 + j * 16 + lr;
        const float bb = bias[gn];
#pragma unroll
        for (int r = 0; r < 4; ++r)
          C[(size_t)(gm + r) * HIDN + gn] = acc[f][j][r] + bb;
      }
    }
  } else {
    // LDS-staged coalesced bf16 epilogue, R13: XOR-swizzled both sides.
    __builtin_amdgcn_s_barrier();
    __builtin_amdgcn_sched_barrier(0);
    char* wlds = smem + wid * 16384;
#pragma unroll
    for (int f = 0; f < 8; ++f) {
#pragma unroll
      for (int j = 0; j < 4; ++j) {
        const int gn = n0 + wc * 64 + j * 16 + lr;
        const float bb = bias[gn];
#pragma unroll
        for (int r = 0; r < 4; ++r) {
          const int row = f * 16 + lh * 4 + r;
          const int col2 = ((j * 16 + lr) * 2) ^ ((row & 7) << 4);
          *(bf16_t*)(wlds + row * 128 + col2) = (bf16_t)(acc[f][j][r] + bb);
        }
      }
    }
    asm volatile("s_waitcnt lgkmcnt(0)" ::: "memory");
    __builtin_amdgcn_sched_barrier(0);
    bf16_t* C = (bf16_t*)Cout;
    const int gnb = n0 + wc * 64;
    const int h = gnb >> 7, dd = gnb & 127;
#pragma unroll
    for (int p = 0; p < 16; ++p) {
      const int rl = p * 8 + (lane >> 3);
      const int cb = ((lane & 7) * 16) ^ ((rl & 7) << 4);
      const uint4 v = *(const uint4*)(wlds + rl * 128 + cb);
      const int gm = m0 + wr * 128 + rl;
      const int b = gm >> 12, l = gm & 4095;
      char* dstp = (char*)(C + (((size_t)(b * NHEAD + h) * LQLEN + l) << 7) + dd) +
                   (((lane & 7) * 16));
      // note: global dest uses the UN-swizzled column (cb ^ swizzle restores it)
      *(uint4*)dstp = v;
    }
  }
}

// Merged Q-proj + A-proj: blocks [0,512) -> query, [512,1024) -> atten.
__global__ __launch_bounds__(512, 2) void gemm_qa(
    const float* __restrict__ Aq, const bf16_t* __restrict__ Wq,
    const float* __restrict__ bq, bf16_t* __restrict__ Qh,
    const float* __restrict__ Aa, const bf16_t* __restrict__ Wa,
    const float* __restrict__ ba, bf16_t* __restrict__ Ah) {
  __shared__ uint4 smem_raw[8192];  // 128KB
  const int bid = blockIdx.x;
  if (bid < 512)
    gemm8p_body<0, true>(Aq, Wq, bq, (void*)Qh, (char*)smem_raw, bid);
  else
    gemm8p_body<0, true>(Aa, Wa, ba, (void*)Ah, (char*)smem_raw, bid - 512);
}

// FC GEMM (bf16 A path)
__global__ __launch_bounds__(512, 2) void gemm_fc(const bf16_t* __restrict__ A,
                                                  const bf16_t* __restrict__ Bw,
                                                  const float* __restrict__ bias,
                                                  float* __restrict__ Cout) {
  __shared__ uint4 smem_raw[8192];  // 128KB
  gemm8p_body<2, false>(A, Bw, bias, (void*)Cout, (char*)smem_raw, blockIdx.x);
}

// ---------------------------------------------------------------------------
// Merged K+V projections (M = 1024): z=0 -> K (head layout), z=1 -> V (V^T)
// ---------------------------------------------------------------------------
__global__ __launch_bounds__(256) void gemm_btkv(
    const bf16_t* __restrict__ kA, const bf16_t* __restrict__ kW,
    const float* __restrict__ kb_, bf16_t* __restrict__ Kh,
    const bf16_t* __restrict__ vA, const bf16_t* __restrict__ vW,
    const float* __restrict__ vb_, bf16_t* __restrict__ Vt) {
  constexpr int BK = 32;
  __shared__ uint4 AsRaw[128 * BK * 2 / 16];
  __shared__ uint4 BsRaw[128 * BK * 2 / 16];
  bf16_t* As = (bf16_t*)AsRaw;
  bf16_t* Bs = (bf16_t*)BsRaw;

  const bool isV = (blockIdx.z == 1);
  const bf16_t* A = isV ? vA : kA;
  const bf16_t* Bw = isV ? vW : kW;
  const float* bias = isV ? vb_ : kb_;
  bf16_t* Cout = isV ? Vt : Kh;

  const int tid = threadIdx.x;
  const int wid = tid >> 6;
  const int lane = tid & 63;
  const int lr = lane & 15, lh = lane >> 4;
  const int m0 = blockIdx.x * 128, n0 = blockIdx.y * 128;
  const int wm = (wid >> 1) * 64, wn = (wid & 1) * 64;

  f32x4 acc[4][4] = {};

  const int srow = lane >> 2;
  const int scol = (lane & 3) * 16;

  for (int k0 = 0; k0 < HIDN; k0 += BK) {
#pragma unroll
    for (int i = 0; i < 2; ++i) {
      const int c = wid + i * 4;
      const int row = c * 16 + srow;
      gload_lds16((const char*)A + ((size_t)(m0 + row) * HIDN + k0) * 2 + scol,
                  (char*)As + c * 1024);
      gload_lds16((const char*)Bw + ((size_t)(n0 + row) * HIDN + k0) * 2 + scol,
                  (char*)Bs + c * 1024);
    }
    __syncthreads();

    bf16x8 af[4], bfr[4];
#pragma unroll
    for (int i = 0; i < 4; ++i) {
      af[i]  = *(const bf16x8*)(As + (wm + i * 16 + lr) * BK + lh * 8);
      bfr[i] = *(const bf16x8*)(Bs + (wn + i * 16 + lr) * BK + lh * 8);
    }
#pragma unroll
    for (int i = 0; i < 4; ++i)
#pragma unroll
      for (int j = 0; j < 4; ++j)
        acc[i][j] = __builtin_amdgcn_mfma_f32_16x16x32_bf16(af[i], bfr[j], acc[i][j], 0, 0, 0);
    __syncthreads();
  }

#pragma unroll
  for (int i = 0; i < 4; ++i) {
#pragma unroll
    for (int r = 0; r < 4; ++r) {
      const int gm = m0 + wm + i * 16 + lh * 4 + r;
#pragma unroll
      for (int j = 0; j < 4; ++j) {
        const int gn = n0 + wn + j * 16 + lr;
        const float v = acc[i][j][r] + bias[gn];
        const int b = gm >> 7, l = gm & 127;
        const int h = gn >> 7, d = gn & 127;
        size_t idx;
        if (!isV)
          idx = (((size_t)(b * NHEAD + h) * 128 + l) << 7) + d;
        else
          idx = (((size_t)(b * NHEAD + h) * 128 + d) << 7) + l;
        Cout[idx] = (bf16_t)v;
      }
    }
  }
}

// ---------------------------------------------------------------------------
// Fused attention (R11 + R13 XCD remap + __expf)
// ---------------------------------------------------------------------------
__global__ __launch_bounds__(256) void attn_kernel(
    const bf16_t* __restrict__ Qh, const bf16_t* __restrict__ Ah,
    const bf16_t* __restrict__ Kh, const bf16_t* __restrict__ Vt,
    const int* __restrict__ mask, bf16_t* __restrict__ X) {
  __shared__ uint4 KsRaw[2048];
  __shared__ uint4 VsRaw[2048];
  __shared__ float Ms[128];
  char* Ks = (char*)KsRaw;
  char* Vs = (char*)VsRaw;

  const int tid = threadIdx.x, wid = tid >> 6, lane = tid & 63;
  const int lr = lane & 15, lh = lane >> 4;

  // XCD-aware remap (bijective, 4096 % 8 == 0): each XCD owns 8 contiguous
  // heads -> its K/V working set (8 x 32KB) lives in its private L2.
  const int lin = blockIdx.y * 64 + blockIdx.x;
  const int nid = (lin & 7) * 512 + (lin >> 3);
  const int bh = nid >> 6, b = bh >> 3, h = bh & 7;
  const int q0 = (nid & 63) * 64;

  {
    const char* Kg = (const char*)(Kh + (size_t)bh * 16384);
    const char* Vg = (const char*)(Vt + (size_t)bh * 16384);
#pragma unroll
    for (int it = 0; it < 8; ++it) {
      const int e = it * 256 + tid;
      const int row = e >> 4;
      const int cbp = (e & 15) << 4;
      const int srcoff = row * 256 + (cbp ^ ((row & 7) << 4));
      gload_lds16(Kg + srcoff, Ks + e * 16);
      gload_lds16(Vg + srcoff, Vs + e * 16);
    }
  }
  if (tid < 128) Ms[tid] = (mask[b * 128 + tid] == 0) ? 0.f : 1.f;

  bf16x8 qf[4];
  {
    const bf16_t* Qb = Qh + ((size_t)bh * LQLEN + q0 + wid * 16 + lr) * 128;
#pragma unroll
    for (int s = 0; s < 4; ++s) qf[s] = *(const bf16x8*)(Qb + s * 32 + lh * 8);
  }
  asm volatile("s_waitcnt vmcnt(0)" ::: "memory");
  __syncthreads();

  f32x4 acc[8] = {};
#pragma unroll
  for (int nt = 0; nt < 8; ++nt) {
#pragma unroll
    for (int s = 0; s < 4; ++s) {
      const int row = nt * 16 + lr;
      const int cb = (s * 64 + lh * 16) ^ ((row & 7) << 4);
      const bf16x8 kf = *(const bf16x8*)(Ks + row * 256 + cb);
      acc[nt] = __builtin_amdgcn_mfma_f32_16x16x32_bf16(qf[s], kf, acc[nt], 0, 0, 0);
    }
  }
  __syncthreads();

  {
    const char* Ag = (const char*)(Ah + ((size_t)bh * LQLEN + q0) * 128);
#pragma unroll
    for (int it = 0; it < 4; ++it) {
      const int c = it * 256 + tid;
      gload_lds16(Ag + c * 16, Ks + 16384 + c * 16);
    }
  }
  asm volatile("s_waitcnt vmcnt(0)" ::: "memory");
  __syncthreads();
  const char* Al = Ks + 16384;

  float ex[8][4];
  float rsum[4];
  const float sc = 0.08838834764831845f;
#pragma unroll
  for (int r = 0; r < 4; ++r) {
    const int row = lh * 4 + r;
    const int rowg = wid * 16 + row;
    float mx = -3.0e38f;
#pragma unroll
    for (int nt = 0; nt < 8; ++nt) {
      const int col = nt * 16 + lr;
      float e = acc[nt][r] * sc + (float)(*(const bf16_t*)(Al + rowg * 256 + col * 2));
      e = (Ms[col] != 0.f) ? e : -1.0e10f;
      ex[nt][r] = e;
      mx = fmaxf(mx, e);
    }
    mx = fmaxf(mx, __shfl_xor(mx, 1));
    mx = fmaxf(mx, __shfl_xor(mx, 2));
    mx = fmaxf(mx, __shfl_xor(mx, 4));
    mx = fmaxf(mx, __shfl_xor(mx, 8));
    float s_ = 0.f;
#pragma unroll
    for (int nt = 0; nt < 8; ++nt) {
      const float p = __expf(ex[nt][r] - mx);
      ex[nt][r] = p;
      s_ += p;
    }
    s_ += __shfl_xor(s_, 1);
    s_ += __shfl_xor(s_, 2);
    s_ += __shfl_xor(s_, 4);
    s_ += __shfl_xor(s_, 8);
    rsum[r] = s_;
  }

  char* Pb = Ks + wid * 4096;
#pragma unroll
  for (int r = 0; r < 4; ++r) {
    const int row = lh * 4 + r;
#pragma unroll
    for (int nt = 0; nt < 8; ++nt) {
      const int col = nt * 16 + lr;
      const int off = (row * 256 + col * 2) ^ ((row & 7) << 4);
      *(bf16_t*)(Pb + off) = (bf16_t)ex[nt][r];
    }
  }
  __syncthreads();

  bf16x8 pf[4];
#pragma unroll
  for (int s = 0; s < 4; ++s)
    pf[s] = *(const bf16x8*)(Pb + lr * 256 + ((s * 64 + lh * 16) ^ ((lr & 7) << 4)));
  f32x4 acc2[8] = {};
#pragma unroll
  for (int nt = 0; nt < 8; ++nt) {
#pragma unroll
    for (int s = 0; s < 4; ++s) {
      const int row = nt * 16 + lr;
      const int cb = (s * 64 + lh * 16) ^ ((row & 7) << 4);
      const bf16x8 vf = *(const bf16x8*)(Vs + row * 256 + cb);
      acc2[nt] = __builtin_amdgcn_mfma_f32_16x16x32_bf16(pf[s], vf, acc2[nt], 0, 0, 0);
    }
  }
  __syncthreads();

  float rs[4];
#pragma unroll
  for (int r = 0; r < 4; ++r) rs[r] = 1.f / rsum[r];
#pragma unroll
  for (int nt = 0; nt < 8; ++nt)
#pragma unroll
    for (int r = 0; r < 4; ++r)
      *(bf16_t*)(Vs + (wid * 16 + lh * 4 + r) * 256 + (nt * 16 + lr) * 2) =
          (bf16_t)(acc2[nt][r] * rs[r]);
  asm volatile("s_waitcnt lgkmcnt(0)" ::: "memory");
  __syncthreads();

#pragma unroll
  for (int it = 0; it < 4; ++it) {
    const int c = it * 256 + tid;
    const int row = c >> 4;
    const int off = (c & 15) << 4;
    const uint4 v = *(const uint4*)(Vs + row * 256 + off);
    char* dstp = (char*)(X + ((size_t)(b * LQLEN) + q0 + row) * HIDN + h * 128) + off;
    *(uint4*)dstp = v;
  }
}

// ---------------------------------------------------------------------------
extern "C" void kernel_launch(void* const* d_in, const int* in_sizes, int n_in,
                              void* d_out, int out_size, void* d_ws, size_t ws_size,
                              hipStream_t stream) {
  const float* query = (const float*)d_in[0];
  const float* key   = (const float*)d_in[1];
  const float* value = (const float*)d_in[2];
  const float* atten = (const float*)d_in[3];
  const int*   mask  = (const int*)d_in[4];
  const float* Wq  = (const float*)d_in[5];  const float* bq   = (const float*)d_in[6];
  const float* Wk  = (const float*)d_in[7];  const float* bk   = (const float*)d_in[8];
  const float* Wv  = (const float*)d_in[9];  const float* bv   = (const float*)d_in[10];
  const float* Wat = (const float*)d_in[11]; const float* batt = (const float*)d_in[12];
  const float* Wfc = (const float*)d_in[13]; const float* bfc  = (const float*)d_in[14];

  char* ws = (char*)d_ws;
  bf16_t* X   = (bf16_t*)(ws + 0x0000000);   // 64MB [B,LQ,HID] bf16 (attn out)
  bf16_t* Qh  = (bf16_t*)(ws + 0x8000000);   // 64MB [B,H,LQ,HD]
  bf16_t* Ah  = (bf16_t*)(ws + 0xC000000);   // 64MB
  char* sm = ws + 0x10000000;
  bf16_t* kbf = (bf16_t*)(sm + 0x000000);
  bf16_t* vbf = (bf16_t*)(sm + 0x200000);
  bf16_t* wqb = (bf16_t*)(sm + 0x400000);
  bf16_t* wkb = (bf16_t*)(sm + 0x600000);
  bf16_t* wvb = (bf16_t*)(sm + 0x800000);
  bf16_t* wab = (bf16_t*)(sm + 0xA00000);
  bf16_t* wfb = (bf16_t*)(sm + 0xC00000);
  bf16_t* Kh  = (bf16_t*)(sm + 0xE00000);
  bf16_t* Vt  = (bf16_t*)(sm + 0x1000000);

  // single batched convert: key, value, 5 weights (1M elems each)
  convk7<<<dim3(256, 7), dim3(256), 0, stream>>>(
      key, value, Wq, Wk, Wv, Wat, Wfc,
      kbf, vbf, wqb, wkb, wvb, wab, wfb);

  // merged K/V projections (one dispatch)
  gemm_btkv<<<dim3(8, 8, 2), dim3(256), 0, stream>>>(
      kbf, wkb, bk, Kh, vbf, wvb, bv, Vt);

  // merged Q-proj + A-proj (one dispatch, fused f32 convert)
  gemm_qa<<<dim3(1024), dim3(512), 0, stream>>>(
      query, wqb, bq, Qh, atten, wab, batt, Ah);

  // fused attention
  attn_kernel<<<dim3(LQLEN / 64, NBATCH * NHEAD), dim3(256), 0, stream>>>(
      Qh, Ah, Kh, Vt, mask, X);

  // final FC -> f32 out
  gemm_fc<<<dim3(512), dim3(512), 0, stream>>>(X, wfb, bfc, (float*)d_out);
}